// Round 5
// baseline (130.714 us; speedup 1.0000x reference)
//
#include <hip/hip_runtime.h>

#define RES 8
#define F 512      // RES^3
#define CLASSES 40
#define B 64
#define NPTS 100000
#define NSLOT (NPTS / 4)   // 25000 slots; slot = 4 points = 3 float4 loads

// 16 blocks per batch: 64*16 = 1024 blocks = exactly 4 blocks/CU on 256 CUs.
// 4 blocks/CU is an achievable tier (VGPR <= 128 via __launch_bounds__(256,4);
// LDS ~10.8 KB/block). Cooperative launch is used ONLY for the co-residency
// guarantee (makes the per-batch spin barriers deadlock-free); no grid.sync.
#define BLKS 16

// Flag value: ws is re-poisoned by the harness before each iteration, so
// flags reset. Poison patterns (0x00/0xFF/0xAB../NaN) never equal MAGIC.
#define MAGIC 0x5F3A9C71u

// ws layout (4-byte units). Everything is write-before-read except the spin
// flags, which rely on poison != MAGIC.
// PARTH : B*BLKS*F uints       — per-block partial histograms (2 MB)
// PARTMM: B*BLKS*6 floats      — per-block partial min(0..2)/max(3..5)
// FLAGMM/FLAGH: B*BLKS flags, stride 16 uints (64 B) to avoid line sharing
#define PARTH_OFF 0
#define PARTMM_OFF (B * BLKS * F)
#define FLAGMM_OFF (PARTMM_OFF + B * BLKS * 6)
#define FLAGH_OFF  (FLAGMM_OFF + B * BLKS * 16)

__global__ __launch_bounds__(256, 4) void fused_kernel(const float* __restrict__ x,
                                                       const float* __restrict__ Wm,
                                                       const float* __restrict__ bias,
                                                       float* __restrict__ out,
                                                       unsigned int* __restrict__ ws) {
    const int sub   = blockIdx.x;   // 0..BLKS-1
    const int batch = blockIdx.y;   // 0..B-1
    const int t     = threadIdx.x;

    __shared__ unsigned int lh[4][F];       // per-wave sub-histograms (8 KB)
    __shared__ float red[6][BLKS];
    __shared__ float smn[3], ssc[3];
    __shared__ float wmin[4][3], wmax[4][3];
    __shared__ float cf[F];

    for (int i = t; i < 4 * F; i += 256) ((unsigned int*)lh)[i] = 0u;

    const float4* xb4 = (const float4*)(x + (size_t)batch * (NPTS * 3));

    // ---------------- phase 1: per-block min/max (slot pattern) -------------
    {
        float m0 = 3.0e38f, m1 = 3.0e38f, m2 = 3.0e38f;
        float M0 = -3.0e38f, M1 = -3.0e38f, M2 = -3.0e38f;
#pragma unroll 2
        for (int i = sub * 256 + t; i < NSLOT; i += BLKS * 256) {
            float4 p0 = xb4[3 * i + 0];
            float4 p1 = xb4[3 * i + 1];
            float4 p2 = xb4[3 * i + 2];
            m0 = fminf(m0, fminf(fminf(p0.x, p0.w), fminf(p1.z, p2.y)));
            M0 = fmaxf(M0, fmaxf(fmaxf(p0.x, p0.w), fmaxf(p1.z, p2.y)));
            m1 = fminf(m1, fminf(fminf(p0.y, p1.x), fminf(p1.w, p2.z)));
            M1 = fmaxf(M1, fmaxf(fmaxf(p0.y, p1.x), fmaxf(p1.w, p2.z)));
            m2 = fminf(m2, fminf(fminf(p0.z, p1.y), fminf(p2.x, p2.w)));
            M2 = fmaxf(M2, fmaxf(fmaxf(p0.z, p1.y), fmaxf(p2.x, p2.w)));
        }
        for (int d = 1; d < 64; d <<= 1) {
            m0 = fminf(m0, __shfl_xor(m0, d)); M0 = fmaxf(M0, __shfl_xor(M0, d));
            m1 = fminf(m1, __shfl_xor(m1, d)); M1 = fmaxf(M1, __shfl_xor(M1, d));
            m2 = fminf(m2, __shfl_xor(m2, d)); M2 = fmaxf(M2, __shfl_xor(M2, d));
        }
        const int wave = t >> 6;
        if ((t & 63) == 0) {
            wmin[wave][0] = m0; wmin[wave][1] = m1; wmin[wave][2] = m2;
            wmax[wave][0] = M0; wmax[wave][1] = M1; wmax[wave][2] = M2;
        }
        __syncthreads();
        if (t < 3) {
            float mn = fminf(fminf(wmin[0][t], wmin[1][t]), fminf(wmin[2][t], wmin[3][t]));
            float mx = fmaxf(fmaxf(wmax[0][t], wmax[1][t]), fmaxf(wmax[2][t], wmax[3][t]));
            float* pm = (float*)(ws + PARTMM_OFF) + ((size_t)batch * BLKS + sub) * 6;
            pm[t]     = mn;
            pm[3 + t] = mx;
        }
    }

    // ---------------- per-batch barrier #1 (16 flags) -----------------------
    __syncthreads();                       // pm writes done block-wide
    if (t == 0) {
        __threadfence();                   // publish pm
        __hip_atomic_store(&ws[FLAGMM_OFF + (batch * BLKS + sub) * 16], MAGIC,
                           __ATOMIC_RELEASE, __HIP_MEMORY_SCOPE_AGENT);
    }
    if (t < BLKS) {
        const unsigned int* fl = &ws[FLAGMM_OFF + (batch * BLKS + t) * 16];
        while (__hip_atomic_load(fl, __ATOMIC_ACQUIRE, __HIP_MEMORY_SCOPE_AGENT) != MAGIC)
            __builtin_amdgcn_s_sleep(2);
    }
    __syncthreads();
    __threadfence();

    // ---------------- phase 2: reduce this batch's min/max ------------------
    {
        const float* pm = (const float*)(ws + PARTMM_OFF) + (size_t)batch * BLKS * 6;
        if (t < 6 * BLKS) {                  // c = t%6, j = t/6 in [0,BLKS)
            const int c = t % 6, j = t / 6;
            red[c][j] = pm[j * 6 + c];
        }
        __syncthreads();
        if (t < 3) {
            float mn = red[t][0], mx = red[t + 3][0];
#pragma unroll
            for (int j = 1; j < BLKS; ++j) {
                mn = fminf(mn, red[t][j]);
                mx = fmaxf(mx, red[t + 3][j]);
            }
            float rng = mx - mn;
            smn[t] = mn;
            ssc[t] = (float)RES / (rng > 0.0f ? rng : 1.0f);  // same fp32 div as ref
        }
        __syncthreads();
    }

    // ---------------- phase 3: histogram (x LLC-resident from phase 1) ------
    {
        const float mn0 = smn[0], mn1 = smn[1], mn2 = smn[2];
        const float sc0 = ssc[0], sc1 = ssc[1], sc2 = ssc[2];
        unsigned int* myh = lh[t >> 6];

        for (int i = sub * 256 + t; i < NSLOT; i += BLKS * 256) {
            float4 p0 = xb4[3 * i + 0];
            float4 p1 = xb4[3 * i + 1];
            float4 p2 = xb4[3 * i + 2];
            float px[4][3] = {{p0.x, p0.y, p0.z},
                              {p0.w, p1.x, p1.y},
                              {p1.z, p1.w, p2.x},
                              {p2.y, p2.z, p2.w}};
#pragma unroll
            for (int q = 0; q < 4; ++q) {
                int i0 = (int)floorf((px[q][0] - mn0) * sc0);
                int i1 = (int)floorf((px[q][1] - mn1) * sc1);
                int i2 = (int)floorf((px[q][2] - mn2) * sc2);
                i0 = min(max(i0, 0), RES - 1);
                i1 = min(max(i1, 0), RES - 1);
                i2 = min(max(i2, 0), RES - 1);
                atomicAdd(&myh[(i0 * RES + i1) * RES + i2], 1u);
            }
        }
        __syncthreads();
    }

    // sub != 0: publish partial histogram, set done flag, EXIT (no barrier).
    if (sub != 0) {
        unsigned int* ph = ws + PARTH_OFF + ((size_t)batch * BLKS + sub) * F;
        for (int bin = t; bin < F; bin += 256)
            ph[bin] = lh[0][bin] + lh[1][bin] + lh[2][bin] + lh[3][bin];
        __syncthreads();
        if (t == 0) {
            __threadfence();
            __hip_atomic_store(&ws[FLAGH_OFF + (batch * BLKS + sub) * 16], MAGIC,
                               __ATOMIC_RELEASE, __HIP_MEMORY_SCOPE_AGENT);
        }
        return;
    }

    // ---------------- phase 4 (sub==0): wait 15 peers, reduce + logits ------
    if (t >= 1 && t < BLKS) {
        const unsigned int* fl = &ws[FLAGH_OFF + (batch * BLKS + t) * 16];
        while (__hip_atomic_load(fl, __ATOMIC_ACQUIRE, __HIP_MEMORY_SCOPE_AGENT) != MAGIC)
            __builtin_amdgcn_s_sleep(2);
    }
    __syncthreads();
    __threadfence();
    {
        const unsigned int* ph = ws + PARTH_OFF + (size_t)batch * BLKS * F;
        for (int bin = t; bin < F; bin += 256) {
            unsigned int s = lh[0][bin] + lh[1][bin] + lh[2][bin] + lh[3][bin];
#pragma unroll
            for (int j = 1; j < BLKS; ++j) s += ph[j * F + bin];
            cf[bin] = (float)s * (1.0f / (float)NPTS);
        }
        __syncthreads();
        if (t < CLASSES) {
            const float4* wr  = (const float4*)(Wm + t * F);
            const float4* cf4 = (const float4*)cf;
            float d0 = 0.f, d1 = 0.f, d2 = 0.f, d3 = 0.f;
#pragma unroll 4
            for (int k = 0; k < F / 4; k += 4) {
                float4 w0 = wr[k],   c0 = cf4[k];
                float4 w1 = wr[k+1], c1 = cf4[k+1];
                float4 w2 = wr[k+2], c2 = cf4[k+2];
                float4 w3 = wr[k+3], c3 = cf4[k+3];
                d0 += c0.x*w0.x + c0.y*w0.y + c0.z*w0.z + c0.w*w0.w;
                d1 += c1.x*w1.x + c1.y*w1.y + c1.z*w1.z + c1.w*w1.w;
                d2 += c2.x*w2.x + c2.y*w2.y + c2.z*w2.z + c2.w*w2.w;
                d3 += c3.x*w3.x + c3.y*w3.y + c3.z*w3.z + c3.w*w3.w;
            }
            out[batch * CLASSES + t] = ((d0 + d1) + (d2 + d3)) + bias[t];
        }
    }
}

// ---------------------------------------------------------------------------
// Fallback 3-kernel path (used only if cooperative co-residency check fails).
// No spins -> safe under any occupancy. Same ws layout, same arithmetic.
// ---------------------------------------------------------------------------
__global__ __launch_bounds__(256) void minmax_kernel(const float* __restrict__ x,
                                                     unsigned int* __restrict__ ws) {
    const int sub = blockIdx.x, batch = blockIdx.y, t = threadIdx.x;
    const float4* xb4 = (const float4*)(x + (size_t)batch * (NPTS * 3));
    float m0 = 3.0e38f, m1 = 3.0e38f, m2 = 3.0e38f;
    float M0 = -3.0e38f, M1 = -3.0e38f, M2 = -3.0e38f;
    for (int i = sub * 256 + t; i < NSLOT; i += BLKS * 256) {
        float4 p0 = xb4[3 * i + 0];
        float4 p1 = xb4[3 * i + 1];
        float4 p2 = xb4[3 * i + 2];
        m0 = fminf(m0, fminf(fminf(p0.x, p0.w), fminf(p1.z, p2.y)));
        M0 = fmaxf(M0, fmaxf(fmaxf(p0.x, p0.w), fmaxf(p1.z, p2.y)));
        m1 = fminf(m1, fminf(fminf(p0.y, p1.x), fminf(p1.w, p2.z)));
        M1 = fmaxf(M1, fmaxf(fmaxf(p0.y, p1.x), fmaxf(p1.w, p2.z)));
        m2 = fminf(m2, fminf(fminf(p0.z, p1.y), fminf(p2.x, p2.w)));
        M2 = fmaxf(M2, fmaxf(fmaxf(p0.z, p1.y), fmaxf(p2.x, p2.w)));
    }
    for (int d = 1; d < 64; d <<= 1) {
        m0 = fminf(m0, __shfl_xor(m0, d)); M0 = fmaxf(M0, __shfl_xor(M0, d));
        m1 = fminf(m1, __shfl_xor(m1, d)); M1 = fmaxf(M1, __shfl_xor(M1, d));
        m2 = fminf(m2, __shfl_xor(m2, d)); M2 = fmaxf(M2, __shfl_xor(M2, d));
    }
    __shared__ float wmin[4][3], wmax[4][3];
    const int wave = t >> 6;
    if ((t & 63) == 0) {
        wmin[wave][0] = m0; wmin[wave][1] = m1; wmin[wave][2] = m2;
        wmax[wave][0] = M0; wmax[wave][1] = M1; wmax[wave][2] = M2;
    }
    __syncthreads();
    if (t < 3) {
        float mn = fminf(fminf(wmin[0][t], wmin[1][t]), fminf(wmin[2][t], wmin[3][t]));
        float mx = fmaxf(fmaxf(wmax[0][t], wmax[1][t]), fmaxf(wmax[2][t], wmax[3][t]));
        float* pm = (float*)(ws + PARTMM_OFF) + ((size_t)batch * BLKS + sub) * 6;
        pm[t] = mn;
        pm[3 + t] = mx;
    }
}

__global__ __launch_bounds__(256) void hist_kernel(const float* __restrict__ x,
                                                   unsigned int* __restrict__ ws) {
    const int sub = blockIdx.x, batch = blockIdx.y, t = threadIdx.x;
    __shared__ unsigned int lh[4][F];
    __shared__ float red[6][BLKS];
    __shared__ float smn[3], ssc[3];
    for (int i = t; i < 4 * F; i += 256) ((unsigned int*)lh)[i] = 0u;

    const float* pm = (const float*)(ws + PARTMM_OFF) + (size_t)batch * BLKS * 6;
    if (t < 6 * BLKS) {
        const int c = t % 6, j = t / 6;
        red[c][j] = pm[j * 6 + c];
    }
    __syncthreads();
    if (t < 3) {
        float mn = red[t][0], mx = red[t + 3][0];
#pragma unroll
        for (int j = 1; j < BLKS; ++j) {
            mn = fminf(mn, red[t][j]);
            mx = fmaxf(mx, red[t + 3][j]);
        }
        float rng = mx - mn;
        smn[t] = mn;
        ssc[t] = (float)RES / (rng > 0.0f ? rng : 1.0f);
    }
    __syncthreads();

    const float mn0 = smn[0], mn1 = smn[1], mn2 = smn[2];
    const float sc0 = ssc[0], sc1 = ssc[1], sc2 = ssc[2];
    const float4* xb4 = (const float4*)(x + (size_t)batch * (NPTS * 3));
    unsigned int* myh = lh[t >> 6];
    for (int i = sub * 256 + t; i < NSLOT; i += BLKS * 256) {
        float4 p0 = xb4[3 * i + 0];
        float4 p1 = xb4[3 * i + 1];
        float4 p2 = xb4[3 * i + 2];
        float px[4][3] = {{p0.x, p0.y, p0.z},
                          {p0.w, p1.x, p1.y},
                          {p1.z, p1.w, p2.x},
                          {p2.y, p2.z, p2.w}};
#pragma unroll
        for (int q = 0; q < 4; ++q) {
            int i0 = (int)floorf((px[q][0] - mn0) * sc0);
            int i1 = (int)floorf((px[q][1] - mn1) * sc1);
            int i2 = (int)floorf((px[q][2] - mn2) * sc2);
            i0 = min(max(i0, 0), RES - 1);
            i1 = min(max(i1, 0), RES - 1);
            i2 = min(max(i2, 0), RES - 1);
            atomicAdd(&myh[(i0 * RES + i1) * RES + i2], 1u);
        }
    }
    __syncthreads();
    unsigned int* ph = ws + PARTH_OFF + ((size_t)batch * BLKS + sub) * F;
    for (int bin = t; bin < F; bin += 256)
        ph[bin] = lh[0][bin] + lh[1][bin] + lh[2][bin] + lh[3][bin];
}

__global__ __launch_bounds__(256) void logits_kernel(const unsigned int* __restrict__ ws,
                                                     const float* __restrict__ Wm,
                                                     const float* __restrict__ bias,
                                                     float* __restrict__ out) {
    const int batch = blockIdx.x, t = threadIdx.x;
    __shared__ float cf[F];
    const unsigned int* ph = ws + PARTH_OFF + (size_t)batch * BLKS * F;
    for (int bin = t; bin < F; bin += 256) {
        unsigned int s = 0;
#pragma unroll
        for (int j = 0; j < BLKS; ++j) s += ph[j * F + bin];
        cf[bin] = (float)s * (1.0f / (float)NPTS);
    }
    __syncthreads();
    if (t < CLASSES) {
        const float4* wr  = (const float4*)(Wm + t * F);
        const float4* cf4 = (const float4*)cf;
        float d0 = 0.f, d1 = 0.f, d2 = 0.f, d3 = 0.f;
#pragma unroll 4
        for (int k = 0; k < F / 4; k += 4) {
            float4 w0 = wr[k],   c0 = cf4[k];
            float4 w1 = wr[k+1], c1 = cf4[k+1];
            float4 w2 = wr[k+2], c2 = cf4[k+2];
            float4 w3 = wr[k+3], c3 = cf4[k+3];
            d0 += c0.x*w0.x + c0.y*w0.y + c0.z*w0.z + c0.w*w0.w;
            d1 += c1.x*w1.x + c1.y*w1.y + c1.z*w1.z + c1.w*w1.w;
            d2 += c2.x*w2.x + c2.y*w2.y + c2.z*w2.z + c2.w*w2.w;
            d3 += c3.x*w3.x + c3.y*w3.y + c3.z*w3.z + c3.w*w3.w;
        }
        out[batch * CLASSES + t] = ((d0 + d1) + (d2 + d3)) + bias[t];
    }
}

extern "C" void kernel_launch(void* const* d_in, const int* in_sizes, int n_in,
                              void* d_out, int out_size, void* d_ws, size_t ws_size,
                              hipStream_t stream) {
    const float* x    = (const float*)d_in[0];
    const float* Wm   = (const float*)d_in[1];
    const float* bias = (const float*)d_in[2];
    float* out        = (float*)d_out;
    unsigned int* ws  = (unsigned int*)d_ws;

    // One-time host-side co-residency check (graph-capture safe: occupancy
    // query + device props only, no allocations, no stream ops).
    static int coop_ok = -1;
    if (coop_ok < 0) {
        int dev = 0;
        hipGetDevice(&dev);
        hipDeviceProp_t prop{};
        hipGetDeviceProperties(&prop, dev);
        int nb = 0;
        hipError_t e = hipOccupancyMaxActiveBlocksPerMultiprocessor(
            &nb, (const void*)fused_kernel, 256, 0);
        coop_ok = (e == hipSuccess && prop.cooperativeLaunch &&
                   (long)nb * prop.multiProcessorCount >= (long)BLKS * B) ? 1 : 0;
    }

    if (coop_ok) {
        void* args[] = {(void*)&x, (void*)&Wm, (void*)&bias, (void*)&out, (void*)&ws};
        hipLaunchCooperativeKernel((const void*)fused_kernel, dim3(BLKS, B), dim3(256),
                                   args, 0, stream);
    } else {
        minmax_kernel<<<dim3(BLKS, B), 256, 0, stream>>>(x, ws);
        hist_kernel<<<dim3(BLKS, B), 256, 0, stream>>>(x, ws);
        logits_kernel<<<B, 256, 0, stream>>>(ws, Wm, bias, out);
    }
}

// Round 6
// 126.610 us; speedup vs baseline: 1.0324x; 1.0324x over previous
//
#include <hip/hip_runtime.h>
#include <hip/hip_cooperative_groups.h>

namespace cg = cooperative_groups;

#define RES 8
#define F 512      // RES^3
#define CLASSES 40
#define B 64
#define NPTS 100000
#define NSLOT (NPTS / 4)   // 25000 slots; slot = 4 points = 3 float4 loads

// 16 blocks per batch: 64*16 = 1024 blocks = exactly 4 blocks/CU on 256 CUs.
// 4 blocks/CU achievable: VGPR <= 128 (forced by __launch_bounds__(256,4)),
// LDS ~10.8 KB/block. Cooperative launch for grid.sync co-residency.
#define BLKS 16
#define TPB (BLKS * 256)            // 4096 threads per batch
#define NFULL 6                     // unconditional cached slots per thread
#define TAILCUT (NSLOT - NFULL * TPB)   // 424: threads g<424 own a 7th slot

// ws layout (4-byte units). Everything write-before-read (cnt is initialized
// in-kernel before grid.sync, so poison is harmless).
// PARTH : B*BLKS*F uints   — per-block partial histograms (2 MB)
// PARTMM: B*BLKS*6 floats  — per-block partial min(0..2)/max(3..5)
// CNT   : B counters, stride 16 uints (64 B) to avoid line sharing
#define PARTH_OFF 0
#define PARTMM_OFF (B * BLKS * F)
#define CNT_OFF (PARTMM_OFF + B * BLKS * 6)

// Slot = 3 consecutive float4 = 4 points: pA=(x0 y0 z0 x1) pB=(y1 z1 x2 y2)
// pC=(z2 x3 y3 z3).
#define MM4(pA, pB, pC) do { \
    m0 = fminf(m0, fminf(fminf((pA).x, (pA).w), fminf((pB).z, (pC).y))); \
    M0 = fmaxf(M0, fmaxf(fmaxf((pA).x, (pA).w), fmaxf((pB).z, (pC).y))); \
    m1 = fminf(m1, fminf(fminf((pA).y, (pB).x), fminf((pB).w, (pC).z))); \
    M1 = fmaxf(M1, fmaxf(fmaxf((pA).y, (pB).x), fmaxf((pB).w, (pC).z))); \
    m2 = fminf(m2, fminf(fminf((pA).z, (pB).y), fminf((pC).x, (pC).w))); \
    M2 = fmaxf(M2, fmaxf(fmaxf((pA).z, (pB).y), fmaxf((pC).x, (pC).w))); \
} while (0)

#define BIN1(X, Y, Z) do { \
    int i0 = (int)floorf(((X) - mn0) * sc0); \
    int i1 = (int)floorf(((Y) - mn1) * sc1); \
    int i2 = (int)floorf(((Z) - mn2) * sc2); \
    i0 = min(max(i0, 0), RES - 1); \
    i1 = min(max(i1, 0), RES - 1); \
    i2 = min(max(i2, 0), RES - 1); \
    atomicAdd(&myh[(i0 * RES + i1) * RES + i2], 1u); \
} while (0)

#define BIN4(pA, pB, pC) do { \
    BIN1((pA).x, (pA).y, (pA).z); \
    BIN1((pA).w, (pB).x, (pB).y); \
    BIN1((pB).z, (pB).w, (pC).x); \
    BIN1((pC).y, (pC).z, (pC).w); \
} while (0)

__global__ __launch_bounds__(256, 4) void fused_kernel(const float* __restrict__ x,
                                                       const float* __restrict__ Wm,
                                                       const float* __restrict__ bias,
                                                       float* __restrict__ out,
                                                       unsigned int* __restrict__ ws) {
    const int sub   = blockIdx.x;   // 0..BLKS-1
    const int batch = blockIdx.y;   // 0..B-1
    const int t     = threadIdx.x;

    __shared__ unsigned int lh[4][F];       // per-wave sub-histograms (8 KB)
    __shared__ float red[6][BLKS];
    __shared__ float smn[3], ssc[3];
    __shared__ float wmin[4][3], wmax[4][3];
    __shared__ float cf[F];
    __shared__ int swin;

    for (int i = t; i < 4 * F; i += 256) ((unsigned int*)lh)[i] = 0u;

    // Init this batch's arrival counter BEFORE grid.sync (orders it ahead of
    // every post-histogram atomicAdd device-wide).
    if (sub == 0 && t == 0)
        __hip_atomic_store(&ws[CNT_OFF + batch * 16], 0u,
                           __ATOMIC_RELAXED, __HIP_MEMORY_SCOPE_AGENT);

    const float4* xb4 = (const float4*)(x + (size_t)batch * (NPTS * 3));
    const int g = sub * 256 + t;            // 0..4095 within batch
    const float4* bp = xb4 + 3 * g;         // slot k at bp[12288*k + {0,1,2}]
    const bool tail = (g < TAILCUT);        // 7th slot ownership

    // ---------------- phase 1: load-once min/max; points stay in VGPRs -----
    float4 c0a = bp[0],         c0b = bp[1],         c0c = bp[2];
    float4 c1a = bp[12288],     c1b = bp[12289],     c1c = bp[12290];
    float4 c2a = bp[24576],     c2b = bp[24577],     c2c = bp[24578];
    float4 c3a = bp[36864],     c3b = bp[36865],     c3c = bp[36866];
    float4 c4a = bp[49152],     c4b = bp[49153],     c4c = bp[49154];
    float4 c5a = bp[61440],     c5b = bp[61441],     c5c = bp[61442];

    {
        float m0 = 3.0e38f, m1 = 3.0e38f, m2 = 3.0e38f;
        float M0 = -3.0e38f, M1 = -3.0e38f, M2 = -3.0e38f;
        MM4(c0a, c0b, c0c);
        MM4(c1a, c1b, c1c);
        MM4(c2a, c2b, c2c);
        MM4(c3a, c3b, c3c);
        MM4(c4a, c4b, c4c);
        MM4(c5a, c5b, c5c);
        if (tail) {   // 7th slot: consume transiently (re-read later from LLC)
            float4 ta = bp[73728], tb = bp[73729], tc = bp[73730];
            MM4(ta, tb, tc);
        }
        for (int d = 1; d < 64; d <<= 1) {
            m0 = fminf(m0, __shfl_xor(m0, d)); M0 = fmaxf(M0, __shfl_xor(M0, d));
            m1 = fminf(m1, __shfl_xor(m1, d)); M1 = fmaxf(M1, __shfl_xor(M1, d));
            m2 = fminf(m2, __shfl_xor(m2, d)); M2 = fmaxf(M2, __shfl_xor(M2, d));
        }
        const int wave = t >> 6;
        if ((t & 63) == 0) {
            wmin[wave][0] = m0; wmin[wave][1] = m1; wmin[wave][2] = m2;
            wmax[wave][0] = M0; wmax[wave][1] = M1; wmax[wave][2] = M2;
        }
        __syncthreads();
        if (t < 3) {
            float mn = fminf(fminf(wmin[0][t], wmin[1][t]), fminf(wmin[2][t], wmin[3][t]));
            float mx = fmaxf(fmaxf(wmax[0][t], wmax[1][t]), fmaxf(wmax[2][t], wmax[3][t]));
            float* pm = (float*)(ws + PARTMM_OFF) + ((size_t)batch * BLKS + sub) * 6;
            pm[t]     = mn;
            pm[3 + t] = mx;
        }
    }

    cg::this_grid().sync();   // partial min/max visible device-wide

    // ---------------- phase 2: reduce this batch's min/max ------------------
    {
        const float* pm = (const float*)(ws + PARTMM_OFF) + (size_t)batch * BLKS * 6;
        if (t < 6 * BLKS) {                  // c = t%6, j = t/6 in [0,BLKS)
            const int c = t % 6, j = t / 6;
            red[c][j] = pm[j * 6 + c];
        }
        __syncthreads();
        if (t < 3) {
            float mn = red[t][0], mx = red[t + 3][0];
#pragma unroll
            for (int j = 1; j < BLKS; ++j) {
                mn = fminf(mn, red[t][j]);
                mx = fmaxf(mx, red[t + 3][j]);
            }
            float rng = mx - mn;
            smn[t] = mn;
            ssc[t] = (float)RES / (rng > 0.0f ? rng : 1.0f);  // same fp32 div as ref
        }
        __syncthreads();
    }

    // ---------------- phase 3: histogram straight from registers ------------
    {
        const float mn0 = smn[0], mn1 = smn[1], mn2 = smn[2];
        const float sc0 = ssc[0], sc1 = ssc[1], sc2 = ssc[2];
        unsigned int* myh = lh[t >> 6];

        BIN4(c0a, c0b, c0c);
        BIN4(c1a, c1b, c1c);
        BIN4(c2a, c2b, c2c);
        BIN4(c3a, c3b, c3c);
        BIN4(c4a, c4b, c4c);
        BIN4(c5a, c5b, c5c);
        if (tail) {   // 7th slot: re-read (LLC-hit) and bin
            float4 ta = bp[73728], tb = bp[73729], tc = bp[73730];
            BIN4(ta, tb, tc);
        }
        __syncthreads();

        unsigned int* ph = ws + PARTH_OFF + ((size_t)batch * BLKS + sub) * F;
        for (int bin = t; bin < F; bin += 256)
            ph[bin] = lh[0][bin] + lh[1][bin] + lh[2][bin] + lh[3][bin];
        __syncthreads();
    }

    // ---------------- last-block-wins handoff (no spinning anywhere) --------
    if (t == 0) {
        __threadfence();   // publish ph before the arrival tick
        unsigned int old = __hip_atomic_fetch_add(&ws[CNT_OFF + batch * 16], 1u,
                                                  __ATOMIC_ACQ_REL,
                                                  __HIP_MEMORY_SCOPE_AGENT);
        swin = (old == BLKS - 1);
    }
    __syncthreads();
    if (!swin) return;     // 15 of 16 blocks exit immediately
    __threadfence();       // acquire side for the whole winning block

    // ---------------- phase 4 (last block of this batch): reduce + logits ---
    {
        const unsigned int* ph = ws + PARTH_OFF + (size_t)batch * BLKS * F;
        for (int bin = t; bin < F; bin += 256) {
            unsigned int s = 0;
#pragma unroll
            for (int j = 0; j < BLKS; ++j) s += ph[j * F + bin];
            cf[bin] = (float)s * (1.0f / (float)NPTS);
        }
        __syncthreads();
        if (t < CLASSES) {
            const float4* wr  = (const float4*)(Wm + t * F);
            const float4* cf4 = (const float4*)cf;
            float d0 = 0.f, d1 = 0.f, d2 = 0.f, d3 = 0.f;
#pragma unroll 4
            for (int k = 0; k < F / 4; k += 4) {
                float4 w0 = wr[k],   c0 = cf4[k];
                float4 w1 = wr[k+1], c1 = cf4[k+1];
                float4 w2 = wr[k+2], c2 = cf4[k+2];
                float4 w3 = wr[k+3], c3 = cf4[k+3];
                d0 += c0.x*w0.x + c0.y*w0.y + c0.z*w0.z + c0.w*w0.w;
                d1 += c1.x*w1.x + c1.y*w1.y + c1.z*w1.z + c1.w*w1.w;
                d2 += c2.x*w2.x + c2.y*w2.y + c2.z*w2.z + c2.w*w2.w;
                d3 += c3.x*w3.x + c3.y*w3.y + c3.z*w3.z + c3.w*w3.w;
            }
            out[batch * CLASSES + t] = ((d0 + d1) + (d2 + d3)) + bias[t];
        }
    }
}

// ---------------------------------------------------------------------------
// Fallback 3-kernel path (used only if cooperative co-residency check fails).
// No cross-block handoff -> safe under any occupancy. Same ws layout.
// ---------------------------------------------------------------------------
__global__ __launch_bounds__(256) void minmax_kernel(const float* __restrict__ x,
                                                     unsigned int* __restrict__ ws) {
    const int sub = blockIdx.x, batch = blockIdx.y, t = threadIdx.x;
    const float4* xb4 = (const float4*)(x + (size_t)batch * (NPTS * 3));
    float m0 = 3.0e38f, m1 = 3.0e38f, m2 = 3.0e38f;
    float M0 = -3.0e38f, M1 = -3.0e38f, M2 = -3.0e38f;
    for (int i = sub * 256 + t; i < NSLOT; i += BLKS * 256) {
        float4 pA = xb4[3 * i + 0];
        float4 pB = xb4[3 * i + 1];
        float4 pC = xb4[3 * i + 2];
        MM4(pA, pB, pC);
    }
    for (int d = 1; d < 64; d <<= 1) {
        m0 = fminf(m0, __shfl_xor(m0, d)); M0 = fmaxf(M0, __shfl_xor(M0, d));
        m1 = fminf(m1, __shfl_xor(m1, d)); M1 = fmaxf(M1, __shfl_xor(M1, d));
        m2 = fminf(m2, __shfl_xor(m2, d)); M2 = fmaxf(M2, __shfl_xor(M2, d));
    }
    __shared__ float wmin[4][3], wmax[4][3];
    const int wave = t >> 6;
    if ((t & 63) == 0) {
        wmin[wave][0] = m0; wmin[wave][1] = m1; wmin[wave][2] = m2;
        wmax[wave][0] = M0; wmax[wave][1] = M1; wmax[wave][2] = M2;
    }
    __syncthreads();
    if (t < 3) {
        float mn = fminf(fminf(wmin[0][t], wmin[1][t]), fminf(wmin[2][t], wmin[3][t]));
        float mx = fmaxf(fmaxf(wmax[0][t], wmax[1][t]), fmaxf(wmax[2][t], wmax[3][t]));
        float* pm = (float*)(ws + PARTMM_OFF) + ((size_t)batch * BLKS + sub) * 6;
        pm[t] = mn;
        pm[3 + t] = mx;
    }
}

__global__ __launch_bounds__(256) void hist_kernel(const float* __restrict__ x,
                                                   unsigned int* __restrict__ ws) {
    const int sub = blockIdx.x, batch = blockIdx.y, t = threadIdx.x;
    __shared__ unsigned int lh[4][F];
    __shared__ float red[6][BLKS];
    __shared__ float smn[3], ssc[3];
    for (int i = t; i < 4 * F; i += 256) ((unsigned int*)lh)[i] = 0u;

    const float* pm = (const float*)(ws + PARTMM_OFF) + (size_t)batch * BLKS * 6;
    if (t < 6 * BLKS) {
        const int c = t % 6, j = t / 6;
        red[c][j] = pm[j * 6 + c];
    }
    __syncthreads();
    if (t < 3) {
        float mn = red[t][0], mx = red[t + 3][0];
#pragma unroll
        for (int j = 1; j < BLKS; ++j) {
            mn = fminf(mn, red[t][j]);
            mx = fmaxf(mx, red[t + 3][j]);
        }
        float rng = mx - mn;
        smn[t] = mn;
        ssc[t] = (float)RES / (rng > 0.0f ? rng : 1.0f);
    }
    __syncthreads();

    const float mn0 = smn[0], mn1 = smn[1], mn2 = smn[2];
    const float sc0 = ssc[0], sc1 = ssc[1], sc2 = ssc[2];
    const float4* xb4 = (const float4*)(x + (size_t)batch * (NPTS * 3));
    unsigned int* myh = lh[t >> 6];
    for (int i = sub * 256 + t; i < NSLOT; i += BLKS * 256) {
        float4 pA = xb4[3 * i + 0];
        float4 pB = xb4[3 * i + 1];
        float4 pC = xb4[3 * i + 2];
        BIN4(pA, pB, pC);
    }
    __syncthreads();
    unsigned int* ph = ws + PARTH_OFF + ((size_t)batch * BLKS + sub) * F;
    for (int bin = t; bin < F; bin += 256)
        ph[bin] = lh[0][bin] + lh[1][bin] + lh[2][bin] + lh[3][bin];
}

__global__ __launch_bounds__(256) void logits_kernel(const unsigned int* __restrict__ ws,
                                                     const float* __restrict__ Wm,
                                                     const float* __restrict__ bias,
                                                     float* __restrict__ out) {
    const int batch = blockIdx.x, t = threadIdx.x;
    __shared__ float cf[F];
    const unsigned int* ph = ws + PARTH_OFF + (size_t)batch * BLKS * F;
    for (int bin = t; bin < F; bin += 256) {
        unsigned int s = 0;
#pragma unroll
        for (int j = 0; j < BLKS; ++j) s += ph[j * F + bin];
        cf[bin] = (float)s * (1.0f / (float)NPTS);
    }
    __syncthreads();
    if (t < CLASSES) {
        const float4* wr  = (const float4*)(Wm + t * F);
        const float4* cf4 = (const float4*)cf;
        float d0 = 0.f, d1 = 0.f, d2 = 0.f, d3 = 0.f;
#pragma unroll 4
        for (int k = 0; k < F / 4; k += 4) {
            float4 w0 = wr[k],   c0 = cf4[k];
            float4 w1 = wr[k+1], c1 = cf4[k+1];
            float4 w2 = wr[k+2], c2 = cf4[k+2];
            float4 w3 = wr[k+3], c3 = cf4[k+3];
            d0 += c0.x*w0.x + c0.y*w0.y + c0.z*w0.z + c0.w*w0.w;
            d1 += c1.x*w1.x + c1.y*w1.y + c1.z*w1.z + c1.w*w1.w;
            d2 += c2.x*w2.x + c2.y*w2.y + c2.z*w2.z + c2.w*w2.w;
            d3 += c3.x*w3.x + c3.y*w3.y + c3.z*w3.z + c3.w*w3.w;
        }
        out[batch * CLASSES + t] = ((d0 + d1) + (d2 + d3)) + bias[t];
    }
}

extern "C" void kernel_launch(void* const* d_in, const int* in_sizes, int n_in,
                              void* d_out, int out_size, void* d_ws, size_t ws_size,
                              hipStream_t stream) {
    const float* x    = (const float*)d_in[0];
    const float* Wm   = (const float*)d_in[1];
    const float* bias = (const float*)d_in[2];
    float* out        = (float*)d_out;
    unsigned int* ws  = (unsigned int*)d_ws;

    // One-time host-side co-residency check (graph-capture safe: occupancy
    // query + device props only, no allocations, no stream ops).
    static int coop_ok = -1;
    if (coop_ok < 0) {
        int dev = 0;
        hipGetDevice(&dev);
        hipDeviceProp_t prop{};
        hipGetDeviceProperties(&prop, dev);
        int nb = 0;
        hipError_t e = hipOccupancyMaxActiveBlocksPerMultiprocessor(
            &nb, (const void*)fused_kernel, 256, 0);
        coop_ok = (e == hipSuccess && prop.cooperativeLaunch &&
                   (long)nb * prop.multiProcessorCount >= (long)BLKS * B) ? 1 : 0;
    }

    if (coop_ok) {
        void* args[] = {(void*)&x, (void*)&Wm, (void*)&bias, (void*)&out, (void*)&ws};
        hipLaunchCooperativeKernel((const void*)fused_kernel, dim3(BLKS, B), dim3(256),
                                   args, 0, stream);
    } else {
        minmax_kernel<<<dim3(BLKS, B), 256, 0, stream>>>(x, ws);
        hist_kernel<<<dim3(BLKS, B), 256, 0, stream>>>(x, ws);
        logits_kernel<<<B, 256, 0, stream>>>(ws, Wm, bias, out);
    }
}